// Round 4
// baseline (537.011 us; speedup 1.0000x reference)
//
#include <hip/hip_runtime.h>

// DeltaRule: T=8192 scan over B=4096 independent sequences.
// R4 = R3 with compile fixes: single fused kernel, decoupled look-back.
//  - each tile = (chunk c of 64 steps) x (column of 256 seq-groups)
//  - local affine-map compose + bit-pack x in registers
//  - publish aggregate -> look-back for exclusive prefix -> publish inclusive
//  - replay chunk from exact start state (bits in registers), write out
// x read once (128 MiB), out written once (128 MiB), ~16 MiB scratch traffic.
// Dynamic tile ids (atomic counter) make look-back deadlock-free regardless
// of dispatch order; agent-scope atomics/fences handle cross-XCD L2s.

constexpr int B4     = 1024;            // 4096 seqs / 4 (float4 groups)
constexpr int CHUNK  = 64;
constexpr int NCHUNK = 128;             // 8192 / 64
constexpr int BLOCK  = 256;
constexpr int NCOL   = B4 / BLOCK;      // 4 columns
constexpr int NTILE  = NCOL * NCHUNK;   // 512 tiles
constexpr int COMP   = NTILE * BLOCK;   // float4 elems per map component

typedef float vfloat4 __attribute__((ext_vector_type(4)));

__device__ __forceinline__ float clamp01(float v) {
    return fminf(fmaxf(v, 0.0f), 1.0f);
}

// (Aa,Bb) := (Aa,Bb) ∘ (pA,pB)   [p applied first]
#define COMPOSE4(Aa, Bb, pA, pB)                         \
    Bb.x = fmaf(Aa.x, pB.x, Bb.x);  Aa.x *= pA.x;        \
    Bb.y = fmaf(Aa.y, pB.y, Bb.y);  Aa.y *= pA.y;        \
    Bb.z = fmaf(Aa.z, pB.z, Bb.z);  Aa.z *= pA.z;        \
    Bb.w = fmaf(Aa.w, pB.w, Bb.w);  Aa.w *= pA.w;

__global__ __launch_bounds__(BLOCK) void fused_scan(
    const float4* __restrict__ x4, const float* __restrict__ lr_ptr,
    float4* __restrict__ out4,
    int* __restrict__ counter, int* __restrict__ flags,
    float4* __restrict__ agg, float4* __restrict__ pref)
{
    __shared__ int sTile, sF;
    if (threadIdx.x == 0) sTile = atomicAdd(counter, 1);
    __syncthreads();
    const int tile = sTile;
    const int col  = tile & (NCOL - 1);
    const int c    = tile >> 2;                  // NCOL == 4
    const int i    = col * BLOCK + (int)threadIdx.x;
    const int t0   = c * CHUNK;
    const float lr = clamp01(*lr_ptr);

    // boundary obs = x[t0-1]
    float ob[4];
    if (c == 0) { ob[0]=ob[1]=ob[2]=ob[3]=0.f; }
    else { float4 o = x4[(size_t)(t0 - 1) * B4 + i]; ob[0]=o.x; ob[1]=o.y; ob[2]=o.z; ob[3]=o.w; }

    // ---- local compose + bit-pack ----
    float obs[4] = {ob[0], ob[1], ob[2], ob[3]};
    float A0[4]  = {1,1,1,1}, Bc0[4] = {0,0,0,0};
    float A1[4]  = {1,1,1,1}, Bc1[4] = {0,0,0,0};
    unsigned long long bits[4] = {0,0,0,0};

    #pragma unroll 8
    for (int t = 0; t < CHUNK; ++t) {
        float4 xv = x4[(size_t)(t0 + t) * B4 + i];
        float xt[4] = {xv.x, xv.y, xv.z, xv.w};
        #pragma unroll
        for (int k = 0; k < 4; ++k) {
            bits[k] |= ((unsigned long long)(xt[k] != 0.0f)) << t;
            float g  = 1.0f - obs[k];          // exact: obs ∈ {0,1}
            float l0 = lr * g;
            float l1 = lr - l0;                // exact complement
            float a0 = 1.0f - l0;
            float a1 = 1.0f - l1;
            Bc0[k] = fmaf(a0, Bc0[k], l0 * xt[k]);  A0[k] *= a0;
            Bc1[k] = fmaf(a1, Bc1[k], l1 * xt[k]);  A1[k] *= a1;
            obs[k] = xt[k];
        }
    }

    float4 vA0 = make_float4(A0[0],A0[1],A0[2],A0[3]);
    float4 vB0 = make_float4(Bc0[0],Bc0[1],Bc0[2],Bc0[3]);
    float4 vA1 = make_float4(A1[0],A1[1],A1[2],A1[3]);
    float4 vB1 = make_float4(Bc1[0],Bc1[1],Bc1[2],Bc1[3]);

    const int slot = tile * BLOCK + (int)threadIdx.x;

    // exclusive prefix E (identity for c==0)
    float4 eA0 = make_float4(1,1,1,1), eB0 = make_float4(0,0,0,0);
    float4 eA1 = make_float4(1,1,1,1), eB1 = make_float4(0,0,0,0);

    if (c == 0) {
        pref[0*COMP + slot] = vA0;  pref[1*COMP + slot] = vB0;
        pref[2*COMP + slot] = vA1;  pref[3*COMP + slot] = vB1;
        __syncthreads();                       // all stores drained (vmcnt(0) before barrier)
        if (threadIdx.x == 0)
            __hip_atomic_store(&flags[tile], 2, __ATOMIC_RELEASE, __HIP_MEMORY_SCOPE_AGENT);
    } else {
        agg[0*COMP + slot] = vA0;  agg[1*COMP + slot] = vB0;
        agg[2*COMP + slot] = vA1;  agg[3*COMP + slot] = vB1;
        __syncthreads();
        if (threadIdx.x == 0)
            __hip_atomic_store(&flags[tile], 1, __ATOMIC_RELEASE, __HIP_MEMORY_SCOPE_AGENT);

        // ---- decoupled look-back ----
        int pred = tile - NCOL;
        for (;;) {
            if (threadIdx.x == 0) {
                int f;
                while ((f = __hip_atomic_load(&flags[pred], __ATOMIC_ACQUIRE,
                                              __HIP_MEMORY_SCOPE_AGENT)) == 0)
                    __builtin_amdgcn_s_sleep(1);
                sF = f;
            }
            __syncthreads();
            const int f = sF;
            __syncthreads();
            __builtin_amdgcn_fence(__ATOMIC_ACQUIRE, "agent");
            const float4* __restrict__ src = (f == 2) ? pref : agg;
            const int ps = pred * BLOCK + (int)threadIdx.x;
            float4 pA0 = src[0*COMP + ps], pB0 = src[1*COMP + ps];
            float4 pA1 = src[2*COMP + ps], pB1 = src[3*COMP + ps];
            COMPOSE4(eA0, eB0, pA0, pB0);      // E := E ∘ pred (pred is earlier)
            COMPOSE4(eA1, eB1, pA1, pB1);
            if (f == 2) break;                 // pred's inclusive prefix -> done
            pred -= NCOL;
        }

        // inclusive prefix I = local ∘ E ; publish so successors unblock
        COMPOSE4(vA0, vB0, eA0, eB0);
        COMPOSE4(vA1, vB1, eA1, eB1);
        pref[0*COMP + slot] = vA0;  pref[1*COMP + slot] = vB0;
        pref[2*COMP + slot] = vA1;  pref[3*COMP + slot] = vB1;
        __syncthreads();
        if (threadIdx.x == 0)
            __hip_atomic_store(&flags[tile], 2, __ATOMIC_RELEASE, __HIP_MEMORY_SCOPE_AGENT);
    }

    // ---- replay from exact chunk-start state ----
    float p0[4] = { fmaf(eA0.x, 0.5f, eB0.x), fmaf(eA0.y, 0.5f, eB0.y),
                    fmaf(eA0.z, 0.5f, eB0.z), fmaf(eA0.w, 0.5f, eB0.w) };
    float p1[4] = { fmaf(eA1.x, 0.5f, eB1.x), fmaf(eA1.y, 0.5f, eB1.y),
                    fmaf(eA1.z, 0.5f, eB1.z), fmaf(eA1.w, 0.5f, eB1.w) };
    unsigned lo[4] = { (unsigned)bits[0], (unsigned)bits[1], (unsigned)bits[2], (unsigned)bits[3] };
    unsigned hi[4] = { (unsigned)(bits[0]>>32), (unsigned)(bits[1]>>32),
                       (unsigned)(bits[2]>>32), (unsigned)(bits[3]>>32) };
    float o2[4] = {ob[0], ob[1], ob[2], ob[3]};

    #pragma unroll 8
    for (int t = 0; t < CHUNK; ++t) {
        float pr[4];
        #pragma unroll
        for (int k = 0; k < 4; ++k) {
            unsigned w   = (t < 32) ? lo[k] : hi[k];
            unsigned bit = (w >> (t & 31)) & 1u;
            float xf = (float)bit;             // exact 0.0 / 1.0
            float g  = 1.0f - o2[k];
            float l0 = lr * g;
            float l1 = lr - l0;
            p0[k] = fmaf(l0, xf - p0[k], p0[k]);
            p1[k] = fmaf(l1, xf - p1[k], p1[k]);
            pr[k] = bit ? p1[k] : p0[k];       // exact select, matches ref
            o2[k] = xf;
        }
        vfloat4 v = {pr[0], pr[1], pr[2], pr[3]};
        __builtin_nontemporal_store(v, (vfloat4*)&out4[(size_t)(t0 + t) * B4 + i]);
    }
}

extern "C" void kernel_launch(void* const* d_in, const int* in_sizes, int n_in,
                              void* d_out, int out_size, void* d_ws, size_t ws_size,
                              hipStream_t stream) {
    const float4* x4  = (const float4*)d_in[0];
    const float*  lr  = (const float*)d_in[1];
    float4*       out = (float4*)d_out;

    // ws layout: [0,4) counter | [64, 64+2KiB) flags | 4KiB-aligned: agg (8 MiB) | pref (8 MiB)
    int*    counter = (int*)d_ws;
    int*    flags   = (int*)d_ws + 16;
    float4* agg     = (float4*)((char*)d_ws + 4096);
    float4* pref    = agg + 4 * (size_t)COMP;

    (void)hipMemsetAsync(d_ws, 0, 4096, stream);   // zero counter + flags (graph-capture safe)
    fused_scan<<<dim3(NTILE), BLOCK, 0, stream>>>(x4, lr, out, counter, flags, agg, pref);
}

// Round 5
// 380.106 us; speedup vs baseline: 1.4128x; 1.4128x over previous
//
#include <hip/hip_runtime.h>
#include <hip/hip_cooperative_groups.h>

namespace cg = cooperative_groups;

// DeltaRule: T=8192 scan over B=4096 independent sequences.
// R5: single COOPERATIVE kernel, two grid.sync()s, no look-back chain.
//   Phase A: tile (chunk c, col) composes local affine maps + bit-packs x.
//            Maps stored AoS (64 B per (c,seq-group) slot) -> coalesced writes,
//            and phase B reads one full 64B line per thread (no over-fetch).
//   Phase B: 1024 seq-group scans x 128 chunks == 512 blocks x 256 threads.
//            Kogge-Stone shuffle scan per seq-group; write 32 B start states.
//   Phase C: replay chunk from exact start state using register-resident bits
//            (x never re-read), nontemporal output stores.
// R4's decoupled look-back was a serial 128-link chain (~3us/link = 387us);
// grid sync replaces it with 2 barriers. Phases are memory-bound (4x VALU
// headroom), so inner arithmetic is kept identical to the proven R2 code.

constexpr int B4     = 1024;            // 4096 seqs / 4 (float4 groups)
constexpr int CHUNK  = 64;
constexpr int NCHUNK = 128;             // 8192 / 64
constexpr int BLOCK  = 256;
constexpr int NCOL   = B4 / BLOCK;      // 4 columns
constexpr int NTILE  = NCOL * NCHUNK;   // 512 blocks
constexpr size_t NSLOT = (size_t)NCHUNK * B4;   // 131072 (c,i) slots

typedef float vfloat4 __attribute__((ext_vector_type(4)));

__device__ __forceinline__ float clamp01(float v) {
    return fminf(fmaxf(v, 0.0f), 1.0f);
}

// (Aa,Bb) := (Aa,Bb) ∘ (pA,pB)   [p applied first]
#define COMPOSE4(Aa, Bb, pA, pB)                         \
    Bb.x = fmaf(Aa.x, pB.x, Bb.x);  Aa.x *= pA.x;        \
    Bb.y = fmaf(Aa.y, pB.y, Bb.y);  Aa.y *= pA.y;        \
    Bb.z = fmaf(Aa.z, pB.z, Bb.z);  Aa.z *= pA.z;        \
    Bb.w = fmaf(Aa.w, pB.w, Bb.w);  Aa.w *= pA.w;

__device__ __forceinline__ vfloat4 shfl_up4(vfloat4 v, int d) {
    vfloat4 r;
    r.x = __shfl_up(v.x, d);
    r.y = __shfl_up(v.y, d);
    r.z = __shfl_up(v.z, d);
    r.w = __shfl_up(v.w, d);
    return r;
}

__global__ __launch_bounds__(BLOCK) void fused(
    const float4* __restrict__ x4, const float* __restrict__ lr_ptr,
    float4* __restrict__ out4,
    vfloat4* __restrict__ maps,      // NSLOT*4 vfloat4, slot-major AoS (64 B/slot)
    vfloat4* __restrict__ states)    // NSLOT*2 vfloat4 (32 B/slot: p0,p1)
{
    cg::grid_group grid = cg::this_grid();

    const int tx  = (int)threadIdx.x;
    const int col = (int)blockIdx.x & (NCOL - 1);
    const int c   = (int)blockIdx.x >> 2;          // NCOL == 4
    const int i   = col * BLOCK + tx;              // seq-group 0..B4-1
    const int t0  = c * CHUNK;
    const float lr = clamp01(*lr_ptr);

    // ---------------- Phase A: local compose + bit-pack ----------------
    float ob[4];
    if (c == 0) { ob[0]=ob[1]=ob[2]=ob[3]=0.f; }
    else { float4 o = x4[(size_t)(t0 - 1) * B4 + i]; ob[0]=o.x; ob[1]=o.y; ob[2]=o.z; ob[3]=o.w; }

    float obs[4] = {ob[0], ob[1], ob[2], ob[3]};
    float A0[4]  = {1,1,1,1}, Bc0[4] = {0,0,0,0};
    float A1[4]  = {1,1,1,1}, Bc1[4] = {0,0,0,0};
    unsigned long long bits[4] = {0,0,0,0};

    #pragma unroll 8
    for (int t = 0; t < CHUNK; ++t) {
        float4 xv = x4[(size_t)(t0 + t) * B4 + i];
        float xt[4] = {xv.x, xv.y, xv.z, xv.w};
        #pragma unroll
        for (int k = 0; k < 4; ++k) {
            bits[k] |= ((unsigned long long)(xt[k] != 0.0f)) << t;
            float g  = 1.0f - obs[k];          // exact: obs ∈ {0,1}
            float l0 = lr * g;
            float l1 = lr - l0;                // exact complement
            float a0 = 1.0f - l0;
            float a1 = 1.0f - l1;
            Bc0[k] = fmaf(a0, Bc0[k], l0 * xt[k]);  A0[k] *= a0;
            Bc1[k] = fmaf(a1, Bc1[k], l1 * xt[k]);  A1[k] *= a1;
            obs[k] = xt[k];
        }
    }

    {
        const size_t slot = (size_t)c * B4 + i;
        vfloat4* dst = maps + slot * 4;        // 64 B contiguous per thread
        dst[0] = (vfloat4){A0[0], A0[1], A0[2], A0[3]};
        dst[1] = (vfloat4){Bc0[0], Bc0[1], Bc0[2], Bc0[3]};
        dst[2] = (vfloat4){A1[0], A1[1], A1[2], A1[3]};
        dst[3] = (vfloat4){Bc1[0], Bc1[1], Bc1[2], Bc1[3]};
    }

    grid.sync();

    // ---------------- Phase B: per-seq-group scan over chunks ----------------
    // block = 2 scans; thread -> (g = scan seq-group, cc = chunk), lane = cc&63
    {
        const int g  = (int)blockIdx.x * 2 + (tx >> 7);
        const int cc = tx & 127;
        const int lane = tx & 63;
        const size_t slot = (size_t)cc * B4 + g;
        const vfloat4* src = maps + slot * 4;  // full 64 B line per thread
        vfloat4 sA0 = src[0], sB0 = src[1], sA1 = src[2], sB1 = src[3];

        #pragma unroll
        for (int d = 1; d < 64; d <<= 1) {
            vfloat4 pA0 = shfl_up4(sA0, d), pB0 = shfl_up4(sB0, d);
            vfloat4 pA1 = shfl_up4(sA1, d), pB1 = shfl_up4(sB1, d);
            if (lane >= d) {
                COMPOSE4(sA0, sB0, pA0, pB0);
                COMPOSE4(sA1, sB1, pA1, pB1);
            }
        }

        __shared__ vfloat4 tot[2][4];              // wave-0 total per scan
        __shared__ vfloat4 inc[BLOCK][4];          // inclusive prefixes (16 KiB)

        if (cc == 63) {
            tot[tx >> 7][0] = sA0; tot[tx >> 7][1] = sB0;
            tot[tx >> 7][2] = sA1; tot[tx >> 7][3] = sB1;
        }
        __syncthreads();
        if (cc >= 64) {
            vfloat4 tA0 = tot[tx >> 7][0], tB0 = tot[tx >> 7][1];
            vfloat4 tA1 = tot[tx >> 7][2], tB1 = tot[tx >> 7][3];
            COMPOSE4(sA0, sB0, tA0, tB0);
            COMPOSE4(sA1, sB1, tA1, tB1);
        }
        inc[tx][0] = sA0; inc[tx][1] = sB0; inc[tx][2] = sA1; inc[tx][3] = sB1;
        __syncthreads();

        vfloat4 eA0, eB0, eA1, eB1;                // exclusive = inclusive of cc-1
        if (cc == 0) {
            eA0 = (vfloat4){1,1,1,1}; eB0 = (vfloat4){0,0,0,0};
            eA1 = (vfloat4){1,1,1,1}; eB1 = (vfloat4){0,0,0,0};
        } else {
            eA0 = inc[tx-1][0]; eB0 = inc[tx-1][1];
            eA1 = inc[tx-1][2]; eB1 = inc[tx-1][3];
        }
        // chunk-start state = A*0.5 + B
        vfloat4* sdst = states + slot * 2;         // 32 B contiguous per thread
        sdst[0] = (vfloat4){fmaf(eA0.x, 0.5f, eB0.x), fmaf(eA0.y, 0.5f, eB0.y),
                            fmaf(eA0.z, 0.5f, eB0.z), fmaf(eA0.w, 0.5f, eB0.w)};
        sdst[1] = (vfloat4){fmaf(eA1.x, 0.5f, eB1.x), fmaf(eA1.y, 0.5f, eB1.y),
                            fmaf(eA1.z, 0.5f, eB1.z), fmaf(eA1.w, 0.5f, eB1.w)};
    }

    grid.sync();

    // ---------------- Phase C: replay from exact start state ----------------
    {
        const size_t slot = (size_t)c * B4 + i;
        const vfloat4* ssrc = states + slot * 2;
        vfloat4 P0 = ssrc[0], P1 = ssrc[1];
        float p0[4] = {P0.x, P0.y, P0.z, P0.w};
        float p1[4] = {P1.x, P1.y, P1.z, P1.w};
        unsigned lo[4] = { (unsigned)bits[0], (unsigned)bits[1],
                           (unsigned)bits[2], (unsigned)bits[3] };
        unsigned hi[4] = { (unsigned)(bits[0]>>32), (unsigned)(bits[1]>>32),
                           (unsigned)(bits[2]>>32), (unsigned)(bits[3]>>32) };
        float o2[4] = {ob[0], ob[1], ob[2], ob[3]};

        #pragma unroll 8
        for (int t = 0; t < CHUNK; ++t) {
            float pr[4];
            #pragma unroll
            for (int k = 0; k < 4; ++k) {
                unsigned w   = (t < 32) ? lo[k] : hi[k];
                unsigned bit = (w >> (t & 31)) & 1u;
                float xf = (float)bit;             // exact 0.0 / 1.0
                float g  = 1.0f - o2[k];
                float l0 = lr * g;
                float l1 = lr - l0;
                p0[k] = fmaf(l0, xf - p0[k], p0[k]);
                p1[k] = fmaf(l1, xf - p1[k], p1[k]);
                pr[k] = bit ? p1[k] : p0[k];       // exact select, matches ref
                o2[k] = xf;
            }
            vfloat4 v = {pr[0], pr[1], pr[2], pr[3]};
            __builtin_nontemporal_store(v, (vfloat4*)&out4[(size_t)(t0 + t) * B4 + i]);
        }
    }
}

extern "C" void kernel_launch(void* const* d_in, const int* in_sizes, int n_in,
                              void* d_out, int out_size, void* d_ws, size_t ws_size,
                              hipStream_t stream) {
    const float4* x4  = (const float4*)d_in[0];
    const float*  lr  = (const float*)d_in[1];
    float4*       out = (float4*)d_out;

    // ws: maps 8 MiB (NSLOT*64 B) | states 4 MiB (NSLOT*32 B)
    vfloat4* maps   = (vfloat4*)d_ws;
    vfloat4* states = maps + NSLOT * 4;

    void* args[] = { (void*)&x4, (void*)&lr, (void*)&out,
                     (void*)&maps, (void*)&states };
    (void)hipLaunchCooperativeKernel((const void*)fused,
                                     dim3(NTILE), dim3(BLOCK),
                                     args, 0, stream);
}